// Round 5
// baseline (23.596 us; speedup 1.0000x reference)
//
#include <hip/hip_runtime.h>

// GraphVolterraLayer: N_S=64, N_T=32, N_EFF=2048, K_T1=K_T2=8, BATCH=16.
//
//  k1 (grid 16b x 8 chunks of 8 rows): per b
//      shat = UG^T S_b UPT  -> ws[0..32768)
//      wmat = ((h1c Ub1^T) .* shat) @ UPT -> ws[32768..65536)
//      block 0 also: uhc = UPT[:, :8] @ Hc -> ws[65536..65792)
//  k2 (grid 16b x 32 iT):
//      X = shat .* UPT[iT,:] ;  Gm = X @ UPT[:, :8] ; A = X @ uhc
//      E = HS .* (A Gm^T)  (XOR-chunk-swizzled LDS)
//      z2[iS] = u_iS^T E u_iS  via reg-tiled F = E @ UG^T
//      out = h0 + z1col + z2,  z1col[iS] = sum_kS UG[kS,iS] wmat[kS,iT]

__device__ __forceinline__ int swz(int r, int c) {
  // [64][64] fp32 LDS: row r, elem c at word r*64 + ((c/4 + r/4)&15)*4 + c%4
  return r * 64 + ((((c >> 2) + (r >> 2)) & 15) << 2) + (c & 3);
}

__global__ __launch_bounds__(256) void k1_prepare(
    const float* __restrict__ s, const float* __restrict__ UG,
    const float* __restrict__ UPT, const float* __restrict__ h1c,
    const float* __restrict__ Hc, float* __restrict__ ws)
{
  const int b  = blockIdx.x >> 3;
  const int ch = blockIdx.x & 7;          // rows [8ch, 8ch+8)
  const int t  = threadIdx.x;

  __shared__ float sS[64][33];
  __shared__ float sUPT[32][33];
  __shared__ float sUGc[64][9];           // UG[kS][8ch+rl]
  __shared__ float sh1c[8][9];
  __shared__ float sT1[8][33];
  __shared__ float sY[8][33];

  for (int o = t; o < 2048; o += 256) sS[o >> 5][o & 31] = s[b * 2048 + o];
  for (int o = t; o < 1024; o += 256) sUPT[o >> 5][o & 31] = UPT[o];
  for (int o = t; o < 512;  o += 256) {
    int kS = o >> 3, rl = o & 7;
    sUGc[kS][rl] = UG[kS * 64 + ch * 8 + rl];
  }
  if (t < 64) sh1c[t >> 3][t & 7] = h1c[ch * 64 + t];
  __syncthreads();

  if (blockIdx.x == 0) {                  // uhc[k][p] = sum_q UPT[k,q]*Hc[q,p]
    int k = t >> 3, p = t & 7;
    float a = 0.f;
    #pragma unroll
    for (int q = 0; q < 8; ++q) a += sUPT[k][q] * Hc[q * 8 + p];
    ws[65536 + t] = a;                    // t == k*8+p
  }

  const int rl = t >> 5, c = t & 31;      // one output per thread per phase

  // T1[rl][c] = sum_kS UG[kS][8ch+rl] * S[kS][c]
  float a1 = 0.f;
  #pragma unroll 8
  for (int kS = 0; kS < 64; ++kS) a1 += sUGc[kS][rl] * sS[kS][c];
  sT1[rl][c] = a1;
  __syncthreads();

  // shat -> ws ; Y = (h1c Ub1^T) .* shat
  {
    float sh = 0.f, h1 = 0.f;
    #pragma unroll 8
    for (int k = 0; k < 32; ++k) sh += sT1[rl][k] * sUPT[k][c];
    #pragma unroll
    for (int p = 0; p < 8; ++p) h1 += sh1c[rl][p] * sUPT[c][p];
    ws[b * 2048 + (ch * 8 + rl) * 32 + c] = sh;
    sY[rl][c] = sh * h1;
  }
  __syncthreads();

  // wmat[r][c] = sum_k Y[r][k] * UPT[k][c]
  {
    float a = 0.f;
    #pragma unroll 8
    for (int k = 0; k < 32; ++k) a += sY[rl][k] * sUPT[k][c];
    ws[32768 + b * 2048 + (ch * 8 + rl) * 32 + c] = a;
  }
}

__global__ __launch_bounds__(256) void k2_main(
    const float* __restrict__ ws, const float* __restrict__ UG,
    const float* __restrict__ UPT, const float* __restrict__ h0,
    const float* __restrict__ HS, float* __restrict__ out)
{
  const int b  = blockIdx.x >> 5;
  const int iT = blockIdx.x & 31;
  const int t  = threadIdx.x;

  __shared__ float sX[64][33];                 // shat .* UPT[iT,:]
  __shared__ __align__(16) float sUGf[4096];   // swizzled UG rows
  __shared__ __align__(16) float sEf[4096];    // swizzled E rows
  __shared__ float sUPTb[32][9];
  __shared__ float suhc[32][9];
  __shared__ float poolGA[1152];   // [0,576) Gm, [576,1152) A; P3+: zpart[16][65]
  __shared__ float wvec[64];
  __shared__ float z1c[64];

  // ---- P0: stage ----
  {
    const float4* ug4 = (const float4*)UG;
    float4* dst = (float4*)sUGf;
    for (int o4 = t; o4 < 1024; o4 += 256) {
      int r = o4 >> 4, c4 = o4 & 15;
      dst[r * 16 + ((c4 + (r >> 2)) & 15)] = ug4[o4];
    }
  }
  for (int o = t; o < 2048; o += 256) {
    int k = o & 31;
    sX[o >> 5][k] = ws[b * 2048 + o] * UPT[iT * 32 + k];
  }
  { int k = t >> 3, p = t & 7;
    sUPTb[k][p] = UPT[k * 32 + p];
    suhc[k][p]  = ws[65536 + t]; }
  if (t < 64) wvec[t] = ws[32768 + b * 2048 + t * 32 + iT];
  __syncthreads();

  // ---- P1: Gm = X@UPTb, A = X@uhc (2 rows each/thread); z1 column ----
  {
    const int kSa = t >> 3, p = t & 7;
    float g1 = 0.f, g2 = 0.f, a1 = 0.f, a2 = 0.f;
    #pragma unroll 8
    for (int k = 0; k < 32; ++k) {
      float u = sUPTb[k][p], h = suhc[k][p];
      float x1 = sX[kSa][k], x2 = sX[kSa + 32][k];
      g1 += x1 * u; g2 += x2 * u; a1 += x1 * h; a2 += x2 * h;
    }
    poolGA[kSa * 9 + p]          = g1;
    poolGA[(kSa + 32) * 9 + p]   = g2;
    poolGA[576 + kSa * 9 + p]        = a1;
    poolGA[576 + (kSa + 32) * 9 + p] = a2;
  }
  if (t < 64) {
    float a = 0.f;
    #pragma unroll 8
    for (int kS = 0; kS < 64; ++kS) a += sUGf[swz(kS, t)] * wvec[kS];
    z1c[t] = a;
  }
  __syncthreads();

  // ---- P2: E[kS][lS] = HS .* (A Gm^T), Gm row reg-cached (lS fixed/thread)
  {
    const int lS = t & 63;
    const int kS0 = t >> 6;
    float gr[8];
    #pragma unroll
    for (int p = 0; p < 8; ++p) gr[p] = poolGA[lS * 9 + p];
    #pragma unroll 4
    for (int j = 0; j < 16; ++j) {
      const int kS = 4 * j + kS0;             // o = kS*64+lS == t + 256*j
      float a = 0.f;
      #pragma unroll
      for (int p = 0; p < 8; ++p) a += poolGA[576 + kS * 9 + p] * gr[p];
      sEf[swz(kS, lS)] = a * HS[kS * 64 + lS];
    }
  }
  __syncthreads();

  // ---- P3: F = E @ UG^T reg-tiled 4x4; fuse z2 partials into zpart ----
  float (*zpart)[65] = (float (*)[65])poolGA;   // safe: poolGA dead after P2
  const int ty = t >> 4, tx = t & 15;
  float acc[4][4] = {};
  for (int k4 = 0; k4 < 16; ++k4) {
    float4 ea[4], ub[4];
    const int posE = ((k4 + ty) & 15) << 2;
    #pragma unroll
    for (int i = 0; i < 4; ++i)
      ea[i] = *(const float4*)&sEf[(4 * ty + i) * 64 + posE];
    const int posU = ((k4 + tx) & 15) << 2;
    #pragma unroll
    for (int j = 0; j < 4; ++j)
      ub[j] = *(const float4*)&sUGf[(4 * tx + j) * 64 + posU];
    #pragma unroll
    for (int i = 0; i < 4; ++i)
      #pragma unroll
      for (int j = 0; j < 4; ++j)
        acc[i][j] += ea[i].x * ub[j].x + ea[i].y * ub[j].y +
                     ea[i].z * ub[j].z + ea[i].w * ub[j].w;
  }
  #pragma unroll
  for (int j = 0; j < 4; ++j) {
    const int c = 4 * tx + j;
    float zp = 0.f;
    #pragma unroll
    for (int i = 0; i < 4; ++i) {
      const int addr = c * 64 + (((ty + tx) & 15) << 2) + i;  // swz(c, 4ty+i)
      zp += sUGf[addr] * acc[i][j];
    }
    zpart[ty][c] = zp;
  }
  __syncthreads();

  // ---- P4: reduce zpart (4 threads/col) + write ----
  {
    const int c = t >> 2, q = t & 3;
    float z2 = zpart[q][c] + zpart[q + 4][c] + zpart[q + 8][c] + zpart[q + 12][c];
    z2 += __shfl_xor(z2, 1);
    z2 += __shfl_xor(z2, 2);
    if (q == 0) {
      const int col = c * 32 + iT;
      out[b * 2048 + col] = h0[col] + z1c[c] + z2;
    }
  }
}

extern "C" void kernel_launch(void* const* d_in, const int* in_sizes, int n_in,
                              void* d_out, int out_size, void* d_ws, size_t ws_size,
                              hipStream_t stream) {
  const float* s   = (const float*)d_in[0];  // (16,2048)
  const float* UG  = (const float*)d_in[1];  // (64,64)
  const float* UPT = (const float*)d_in[2];  // (32,32)
  const float* h0  = (const float*)d_in[3];  // (2048,)
  const float* h1c = (const float*)d_in[4];  // (64,8)
  const float* HS  = (const float*)d_in[5];  // (64,64)
  const float* Hc  = (const float*)d_in[6];  // (8,8)
  float* out = (float*)d_out;
  float* ws  = (float*)d_ws;                 // needs 65792 floats ≈ 257 KiB

  k1_prepare<<<128, 256, 0, stream>>>(s, UG, UPT, h1c, Hc, ws);
  k2_main<<<512, 256, 0, stream>>>(ws, UG, UPT, h0, HS, out);
}

// Round 6
// 19.657 us; speedup vs baseline: 1.2004x; 1.2004x over previous
//
#include <hip/hip_runtime.h>

// GraphVolterraLayer: N_S=64, N_T=32, N_EFF=2048, K_T1=K_T2=8, BATCH=16.
//
// ws layout (floats):
//   [0,32768)      shat[16][64][32]
//   [32768,65536)  wmat[16][64][32]
//   [65536,65792)  uhcT[8][32]   (uhc = UPT[:,:8]@Hc, TRANSPOSED [p][k])
//   [65792,66048)  uptbT[8][32]  (UPT[:, :8] transposed [p][k])
//   [66048,70144)  UG bf16 hi[64][64] + lo[64][64], XOR-swizzled (8192 ushort)
//
// k2 per (b,iT):  X = shat .* UPT[iT,:]
//   Gm = X @ UPT[:,:8], A = X @ uhc          (P1, float4 vector LDS)
//   E  = HS .* (A Gm^T) -> bf16 hi/lo LDS    (P2)
//   F  = E @ UG^T via mfma_16x16x32_bf16 x3  (P3, per-wave kS-band)
//   z2[iS] = sum_kS UG[iS,kS] F[kS,iS]       (epilogue, D-layout m89)
//   out = h0 + z1col + z2

typedef short  bf16x8 __attribute__((ext_vector_type(8)));
typedef float  f32x4  __attribute__((ext_vector_type(4)));

static __device__ __forceinline__ unsigned short f2bf(float f) {
  unsigned u = __float_as_uint(f);
  u = (u + 0x7fff + ((u >> 16) & 1)) >> 16;    // RNE
  return (unsigned short)u;
}
static __device__ __forceinline__ float bf2f(unsigned short h) {
  return __uint_as_float(((unsigned)h) << 16);
}

__global__ __launch_bounds__(256) void k1_prepare(
    const float* __restrict__ s, const float* __restrict__ UG,
    const float* __restrict__ UPT, const float* __restrict__ h1c,
    const float* __restrict__ Hc, float* __restrict__ ws)
{
  const int b  = blockIdx.x >> 3;
  const int ch = blockIdx.x & 7;          // rows [8ch, 8ch+8)
  const int t  = threadIdx.x;

  __shared__ float sS[64][33];
  __shared__ float sUPT[32][33];
  __shared__ float sUGc[64][9];           // UG[kS][8ch+rl]
  __shared__ float sh1c[8][9];
  __shared__ float sT1[8][33];
  __shared__ float sY[8][33];

  for (int o = t; o < 2048; o += 256) sS[o >> 5][o & 31] = s[b * 2048 + o];
  for (int o = t; o < 1024; o += 256) sUPT[o >> 5][o & 31] = UPT[o];
  for (int o = t; o < 512;  o += 256) {
    int kS = o >> 3, rl = o & 7;
    sUGc[kS][rl] = UG[kS * 64 + ch * 8 + rl];
  }
  if (t < 64) sh1c[t >> 3][t & 7] = h1c[ch * 64 + t];
  __syncthreads();

  if (blockIdx.x == 0) {
    // uhcT[p][k] = sum_q UPT[k,q]*Hc[q,p]; uptbT[p][k] = UPT[k,p]
    int p = t >> 5, k = t & 31;
    float a = 0.f;
    #pragma unroll
    for (int q = 0; q < 8; ++q) a += sUPT[k][q] * Hc[q * 8 + p];
    ws[65536 + p * 32 + k] = a;
    ws[65792 + p * 32 + k] = sUPT[k][p];
  }
  if (blockIdx.x == 1) {
    // UG -> bf16 hi/lo, XOR-swizzled row-major [64][64]
    unsigned short* wsu = (unsigned short*)(ws + 66048);
    for (int o = t; o < 4096; o += 256) {
      int r = o >> 6, c = o & 63;
      float f = UG[o];
      unsigned short hi = f2bf(f);
      unsigned short lo = f2bf(f - bf2f(hi));
      int sc = c ^ ((r & 7) << 3);
      wsu[r * 64 + sc]        = hi;
      wsu[4096 + r * 64 + sc] = lo;
    }
  }

  const int rl = t >> 5, c = t & 31;

  // T1[rl][c] = sum_kS UG[kS][8ch+rl] * S[kS][c]
  float a1 = 0.f;
  #pragma unroll 8
  for (int kS = 0; kS < 64; ++kS) a1 += sUGc[kS][rl] * sS[kS][c];
  sT1[rl][c] = a1;
  __syncthreads();

  // shat -> ws ; Y = (h1c Ub1^T) .* shat
  {
    float sh = 0.f, h1 = 0.f;
    #pragma unroll 8
    for (int k = 0; k < 32; ++k) sh += sT1[rl][k] * sUPT[k][c];
    #pragma unroll
    for (int p = 0; p < 8; ++p) h1 += sh1c[rl][p] * sUPT[c][p];
    ws[b * 2048 + (ch * 8 + rl) * 32 + c] = sh;
    sY[rl][c] = sh * h1;
  }
  __syncthreads();

  // wmat[r][c] = sum_k Y[r][k] * UPT[k][c]
  {
    float a = 0.f;
    #pragma unroll 8
    for (int k = 0; k < 32; ++k) a += sY[rl][k] * sUPT[k][c];
    ws[32768 + b * 2048 + (ch * 8 + rl) * 32 + c] = a;
  }
}

__global__ __launch_bounds__(256) void k2_main(
    const float* __restrict__ ws, const float* __restrict__ UG,
    const float* __restrict__ UPT, const float* __restrict__ h0,
    const float* __restrict__ HS, float* __restrict__ out)
{
  const int b  = blockIdx.x >> 5;
  const int iT = blockIdx.x & 31;
  const int t  = threadIdx.x;

  __shared__ float sX[64][36];                       // X = shat .* UPT[iT,:]
  __shared__ __align__(16) unsigned short sUGbf[8192];  // hi[4096] | lo[4096]
  __shared__ __align__(16) unsigned short sEbf[8192];   // hi | lo, swizzled
  __shared__ float sGm[64][12];
  __shared__ float sA[64][12];
  __shared__ float sUptbT[8][36];
  __shared__ float sUhcT[8][36];
  __shared__ float wvec[64];
  __shared__ float z1c[64];
  __shared__ float zpart[4][64];

  // ---- P0: stage ----
  {
    const float4* sh4  = (const float4*)(ws + b * 2048);
    const float4* upt4 = (const float4*)(UPT + iT * 32);
    for (int o4 = t; o4 < 512; o4 += 256) {
      int r = o4 >> 3, c = o4 & 7;
      float4 x = sh4[o4], u = upt4[c];
      float4 v; v.x = x.x*u.x; v.y = x.y*u.y; v.z = x.z*u.z; v.w = x.w*u.w;
      *(float4*)&sX[r][c * 4] = v;
    }
    const float4* ug4 = (const float4*)(ws + 66048);
    for (int o4 = t; o4 < 1024; o4 += 256)
      ((float4*)sUGbf)[o4] = ug4[o4];
    for (int o = t; o < 512; o += 256) {
      int m = o >> 8, p = (o >> 5) & 7, k = o & 31;
      float v = ws[65536 + m * 256 + p * 32 + k];
      if (m == 0) sUhcT[p][k] = v; else sUptbT[p][k] = v;
    }
    if (t < 64) wvec[t] = ws[32768 + b * 2048 + t * 32 + iT];
  }
  __syncthreads();

  // ---- P1: Gm = X@UPTb, A = X@uhc (float4); z1 col (wave 0, exact UG) ----
  {
    const int kSa = t >> 3, p = t & 7;
    float g1 = 0.f, g2 = 0.f, a1 = 0.f, a2 = 0.f;
    #pragma unroll
    for (int c = 0; c < 8; ++c) {
      float4 wv = *(const float4*)&sUptbT[p][c * 4];
      float4 hv = *(const float4*)&sUhcT[p][c * 4];
      float4 x1 = *(const float4*)&sX[kSa][c * 4];
      float4 x2 = *(const float4*)&sX[kSa + 32][c * 4];
      g1 += x1.x*wv.x + x1.y*wv.y + x1.z*wv.z + x1.w*wv.w;
      a1 += x1.x*hv.x + x1.y*hv.y + x1.z*hv.z + x1.w*hv.w;
      g2 += x2.x*wv.x + x2.y*wv.y + x2.z*wv.z + x2.w*wv.w;
      a2 += x2.x*hv.x + x2.y*hv.y + x2.z*hv.z + x2.w*hv.w;
    }
    sGm[kSa][p] = g1; sGm[kSa + 32][p] = g2;
    sA[kSa][p]  = a1; sA[kSa + 32][p]  = a2;
  }
  if (t < 64) {
    float a = 0.f;
    #pragma unroll 8
    for (int kS = 0; kS < 64; ++kS) a += UG[kS * 64 + t] * wvec[kS];
    z1c[t] = a;
  }
  __syncthreads();

  // ---- P2: E = HS .* (A Gm^T) -> bf16 hi/lo swizzled ----
  {
    const int w = t >> 6, l = t & 63;
    float4 gr0 = *(const float4*)&sGm[l][0];
    float4 gr1 = *(const float4*)&sGm[l][4];
    #pragma unroll 4
    for (int j = 0; j < 16; ++j) {
      const int kS = 4 * j + w;                     // wave-uniform
      float4 a0 = *(const float4*)&sA[kS][0];
      float4 a1 = *(const float4*)&sA[kS][4];
      float e = (a0.x*gr0.x + a0.y*gr0.y + a0.z*gr0.z + a0.w*gr0.w +
                 a1.x*gr1.x + a1.y*gr1.y + a1.z*gr1.z + a1.w*gr1.w)
                * HS[kS * 64 + l];
      unsigned short hi = f2bf(e);
      unsigned short lo = f2bf(e - bf2f(hi));
      const int sc = l ^ ((kS & 7) << 3);
      sEbf[kS * 64 + sc]        = hi;
      sEbf[4096 + kS * 64 + sc] = lo;
    }
  }
  __syncthreads();

  // ---- P3: F = E @ UG^T via MFMA (bf16 hi/lo, 3 terms); fuse z2 ----
  {
    const int w = t >> 6, l = t & 63;
    const int g = l >> 4, r = l & 15;
    f32x4 acc[4];
    #pragma unroll
    for (int nt = 0; nt < 4; ++nt) acc[nt] = (f32x4){0.f, 0.f, 0.f, 0.f};

    #pragma unroll
    for (int ks = 0; ks < 2; ++ks) {
      const int kcol = g * 8 + ks * 32;             // element col of 8-chunk
      const int rowA = 16 * w + r;
      const int offA = rowA * 64 + (kcol ^ ((rowA & 7) << 3));
      bf16x8 ah = *(const bf16x8*)&sEbf[offA];
      bf16x8 al = *(const bf16x8*)&sEbf[4096 + offA];
      #pragma unroll
      for (int nt = 0; nt < 4; ++nt) {
        const int rowB = 16 * nt + r;
        const int offB = rowB * 64 + (kcol ^ ((rowB & 7) << 3));
        bf16x8 bh = *(const bf16x8*)&sUGbf[offB];
        bf16x8 bl = *(const bf16x8*)&sUGbf[4096 + offB];
        acc[nt] = __builtin_amdgcn_mfma_f32_16x16x32_bf16(ah, bh, acc[nt], 0, 0, 0);
        acc[nt] = __builtin_amdgcn_mfma_f32_16x16x32_bf16(ah, bl, acc[nt], 0, 0, 0);
        acc[nt] = __builtin_amdgcn_mfma_f32_16x16x32_bf16(al, bh, acc[nt], 0, 0, 0);
      }
    }

    // D layout (m89): col = l&15, row = 4*(l>>4)+reg within 16x16 tile.
    // F[kS = 16w+4g+reg][iS = 16nt+r]; z2 partial = UG[iS,kS]*F.
    #pragma unroll
    for (int nt = 0; nt < 4; ++nt) {
      float zp = 0.f;
      #pragma unroll
      for (int reg = 0; reg < 4; ++reg) {
        const int kS = 16 * w + 4 * g + reg;
        const int iS = 16 * nt + r;
        const int uo = iS * 64 + (kS ^ ((iS & 7) << 3));
        const float wug = bf2f(sUGbf[uo]) + bf2f(sUGbf[4096 + uo]);
        zp += wug * acc[nt][reg];
      }
      zp += __shfl_xor(zp, 16);
      zp += __shfl_xor(zp, 32);
      if (g == 0) zpart[w][16 * nt + r] = zp;
    }
  }
  __syncthreads();

  // ---- P4: reduce + write ----
  if (t < 64) {
    float z2 = zpart[0][t] + zpart[1][t] + zpart[2][t] + zpart[3][t];
    const int col = t * 32 + iT;
    out[b * 2048 + col] = h0[col] + z1c[t] + z2;
  }
}

extern "C" void kernel_launch(void* const* d_in, const int* in_sizes, int n_in,
                              void* d_out, int out_size, void* d_ws, size_t ws_size,
                              hipStream_t stream) {
  const float* s   = (const float*)d_in[0];  // (16,2048)
  const float* UG  = (const float*)d_in[1];  // (64,64)
  const float* UPT = (const float*)d_in[2];  // (32,32)
  const float* h0  = (const float*)d_in[3];  // (2048,)
  const float* h1c = (const float*)d_in[4];  // (64,8)
  const float* HS  = (const float*)d_in[5];  // (64,64)
  const float* Hc  = (const float*)d_in[6];  // (8,8)
  float* out = (float*)d_out;
  float* ws  = (float*)d_ws;                 // uses 70144 floats ≈ 274 KiB

  k1_prepare<<<128, 256, 0, stream>>>(s, UG, UPT, h1c, Hc, ws);
  k2_main<<<512, 256, 0, stream>>>(ws, UG, UPT, h0, HS, out);
}

// Round 7
// 14.780 us; speedup vs baseline: 1.5965x; 1.3300x over previous
//
#include <hip/hip_runtime.h>

// GraphVolterraLayer: N_S=64, N_T=32, N_EFF=2048, K_T1=K_T2=8, BATCH=16.
// Single fused kernel, grid 512 = (b,iT), 256 threads (4 waves).
//
// Per block:
//  T1   = UG^T S_b          (MFMA 3-term hi/lo; A = UG cols from global)
//  shat = T1 UPT            (MFMA 3-term; B = UPT^T bf16 staged)
//  Gm/A/Q = shat x {wGm,wA,wQ}   (float4 VALU; folds z1's Q)
//  wv[r] = sum_p h1c[r][p] Q[r][p]  (shuffle-reduce)
//  z1[iS] = sum_kS UG[kS][iS] wv[kS]  (per-wave partials, global UG)
//  E = HS .* (A Gm^T) -> bf16 hi, XOR-swz
//  F = E UG^T via MFMA (hi-only); z2[iS] = sum UG[iS,kS] F[kS,iS]
//  out = h0 + z1 + z2
// mfma convention (validated r6): D[r][c] = sum_k A[r][k]*B[c][k],
// D-layout: col = l&15, row = 4*(l>>4)+reg (m89).

typedef short  bf16x8 __attribute__((ext_vector_type(8)));
typedef float  f32x4  __attribute__((ext_vector_type(4)));

static __device__ __forceinline__ unsigned short f2bf(float f) {
  unsigned u = __float_as_uint(f);
  u = (u + 0x7fff + ((u >> 16) & 1)) >> 16;    // RNE
  return (unsigned short)u;
}
static __device__ __forceinline__ float bf2f(unsigned short h) {
  return __uint_as_float(((unsigned)h) << 16);
}
static __device__ __forceinline__ float dot4(f32x4 a, f32x4 b) {
  return a.x * b.x + a.y * b.y + a.z * b.z + a.w * b.w;
}

__global__ __launch_bounds__(256) void volterra_one(
    const float* __restrict__ s, const float* __restrict__ UG,
    const float* __restrict__ UPT, const float* __restrict__ h0,
    const float* __restrict__ h1c, const float* __restrict__ HS,
    const float* __restrict__ Hc, float* __restrict__ out)
{
  const int b  = blockIdx.x >> 5;
  const int iT = blockIdx.x & 31;
  const int t  = threadIdx.x;
  const int w  = t >> 6;        // wave 0..3
  const int l  = t & 63;
  const int r  = l & 15;
  const int g  = l >> 4;

  __shared__ __align__(16) float sS[64][36];       // S_b, then shat
  __shared__ __align__(16) float sT1E[2304];       // T1 [64][36]; then E bf16 u16[4096]
  __shared__ __align__(16) unsigned short sUGh[4096];      // UG bf16 hi, XOR-swz
  __shared__ __align__(16) unsigned short sUPTTh[32 * 40]; // UPT^T hi (pad-40)
  __shared__ __align__(16) unsigned short sUPTTl[32 * 40]; // UPT^T lo
  __shared__ float sUPT[32][33];
  __shared__ float sUhc[32 * 9];
  __shared__ float sh1c[512];
  __shared__ __align__(16) float wGm[8 * 36];
  __shared__ __align__(16) float wA[8 * 36];
  __shared__ __align__(16) float wQ[8 * 36];
  __shared__ __align__(16) float sGm[64][12];
  __shared__ __align__(16) float sA[64][12];
  __shared__ float wv[64];
  __shared__ float zp1[4][64];
  __shared__ float zpart[4][64];

  // ---- P0: stage ----
  for (int o = t; o < 2048; o += 256) sS[o >> 5][o & 31] = s[b * 2048 + o];
  for (int o = t; o < 1024; o += 256) {
    const int k = o >> 5, c = o & 31;
    const float f = UPT[o];
    sUPT[k][c] = f;
    const unsigned short hi = f2bf(f);
    sUPTTh[c * 40 + k] = hi;
    sUPTTl[c * 40 + k] = f2bf(f - bf2f(hi));
  }
  for (int o = t; o < 4096; o += 256) {
    const int rr = o >> 6, c = o & 63;
    sUGh[rr * 64 + (c ^ ((rr & 7) << 3))] = f2bf(UG[o]);
  }
  for (int o = t; o < 512; o += 256) sh1c[o] = h1c[o];
  {
    const int k = t >> 3, p = t & 7;    // 256 threads
    float a = 0.f;
    #pragma unroll
    for (int q = 0; q < 8; ++q) a += UPT[k * 32 + q] * Hc[q * 8 + p];
    sUhc[k * 9 + p] = a;
  }
  __syncthreads();

  // ---- P1: weight arrays + T1 = UG^T S (MFMA) ----
  {
    const int p = t >> 5, k = t & 31;
    const float uiT_row = sUPT[iT][k];   // UPT[iT,k]  (z2 weights)
    const float uiT_col = sUPT[k][iT];   // UPT[k,iT]  (z1 weight)
    wGm[p * 36 + k] = uiT_row * sUPT[k][p];
    wA [p * 36 + k] = uiT_row * sUhc[k * 9 + p];
    wQ [p * 36 + k] = uiT_col * sUPT[k][p];
  }
  {
    f32x4 acc0 = {0.f, 0.f, 0.f, 0.f}, acc1 = {0.f, 0.f, 0.f, 0.f};
    #pragma unroll
    for (int kc = 0; kc < 2; ++kc) {
      // A[row][k] = UG^T[16w+r][k] = UG[k][16w+r], k = kc*32+g*8+j (global, L2)
      float av[8];
      #pragma unroll
      for (int j = 0; j < 8; ++j)
        av[j] = UG[(kc * 32 + g * 8 + j) * 64 + 16 * w + r];
      bf16x8 Ah, Al;
      #pragma unroll
      for (int j = 0; j < 8; ++j) {
        const unsigned short hi = f2bf(av[j]);
        Ah[j] = (short)hi;
        Al[j] = (short)f2bf(av[j] - bf2f(hi));
      }
      #pragma unroll
      for (int ct = 0; ct < 2; ++ct) {
        // B[c][k] = S[k][c], c = ct*16+r (LDS columns, stride 36)
        float bv[8];
        #pragma unroll
        for (int j = 0; j < 8; ++j)
          bv[j] = sS[kc * 32 + g * 8 + j][ct * 16 + r];
        bf16x8 Bh, Bl;
        #pragma unroll
        for (int j = 0; j < 8; ++j) {
          const unsigned short hi = f2bf(bv[j]);
          Bh[j] = (short)hi;
          Bl[j] = (short)f2bf(bv[j] - bf2f(hi));
        }
        f32x4& acc = ct ? acc1 : acc0;
        acc = __builtin_amdgcn_mfma_f32_16x16x32_bf16(Ah, Bh, acc, 0, 0, 0);
        acc = __builtin_amdgcn_mfma_f32_16x16x32_bf16(Ah, Bl, acc, 0, 0, 0);
        acc = __builtin_amdgcn_mfma_f32_16x16x32_bf16(Al, Bh, acc, 0, 0, 0);
      }
    }
    #pragma unroll
    for (int reg = 0; reg < 4; ++reg) {
      sT1E[(16 * w + 4 * g + reg) * 36 + r]      = acc0[reg];
      sT1E[(16 * w + 4 * g + reg) * 36 + 16 + r] = acc1[reg];
    }
  }
  __syncthreads();

  // ---- P2: shat = T1 @ UPT (MFMA, B = UPT^T staged) -> overwrite sS ----
  {
    f32x4 av0 = *(const f32x4*)&sT1E[(16 * w + r) * 36 + g * 8];
    f32x4 av1 = *(const f32x4*)&sT1E[(16 * w + r) * 36 + g * 8 + 4];
    float av[8] = {av0.x, av0.y, av0.z, av0.w, av1.x, av1.y, av1.z, av1.w};
    bf16x8 Ah, Al;
    #pragma unroll
    for (int j = 0; j < 8; ++j) {
      const unsigned short hi = f2bf(av[j]);
      Ah[j] = (short)hi;
      Al[j] = (short)f2bf(av[j] - bf2f(hi));
    }
    f32x4 acc0 = {0.f, 0.f, 0.f, 0.f}, acc1 = {0.f, 0.f, 0.f, 0.f};
    #pragma unroll
    for (int ct = 0; ct < 2; ++ct) {
      const bf16x8 Bh = *(const bf16x8*)&sUPTTh[(ct * 16 + r) * 40 + g * 8];
      const bf16x8 Bl = *(const bf16x8*)&sUPTTl[(ct * 16 + r) * 40 + g * 8];
      f32x4& acc = ct ? acc1 : acc0;
      acc = __builtin_amdgcn_mfma_f32_16x16x32_bf16(Ah, Bh, acc, 0, 0, 0);
      acc = __builtin_amdgcn_mfma_f32_16x16x32_bf16(Ah, Bl, acc, 0, 0, 0);
      acc = __builtin_amdgcn_mfma_f32_16x16x32_bf16(Al, Bh, acc, 0, 0, 0);
    }
    __syncthreads();   // all P1/P2 reads of sS/sT1E done before shat write
    #pragma unroll
    for (int reg = 0; reg < 4; ++reg) {
      sS[16 * w + 4 * g + reg][r]      = acc0[reg];
      sS[16 * w + 4 * g + reg][16 + r] = acc1[reg];
    }
  }
  __syncthreads();

  // ---- P3a: Gm/A/Q triple-dot (2 rows/thread) + wv shuffle-reduce ----
  {
    const int kSa = t >> 3, p = t & 7;
    float g0 = 0.f, g1v = 0.f, a0 = 0.f, a1v = 0.f, q0 = 0.f, q1v = 0.f;
    #pragma unroll
    for (int c4 = 0; c4 < 8; ++c4) {
      const f32x4 w1 = *(const f32x4*)&wGm[p * 36 + c4 * 4];
      const f32x4 w2 = *(const f32x4*)&wA [p * 36 + c4 * 4];
      const f32x4 w3 = *(const f32x4*)&wQ [p * 36 + c4 * 4];
      const f32x4 x0 = *(const f32x4*)&sS[kSa][c4 * 4];
      const f32x4 x1 = *(const f32x4*)&sS[kSa + 32][c4 * 4];
      g0  += dot4(x0, w1); a0  += dot4(x0, w2); q0  += dot4(x0, w3);
      g1v += dot4(x1, w1); a1v += dot4(x1, w2); q1v += dot4(x1, w3);
    }
    sGm[kSa][p] = g0; sGm[kSa + 32][p] = g1v;
    sA [kSa][p] = a0; sA [kSa + 32][p] = a1v;
    float wv0 = sh1c[kSa * 8 + p] * q0;
    float wv1 = sh1c[(kSa + 32) * 8 + p] * q1v;
    wv0 += __shfl_xor(wv0, 1); wv0 += __shfl_xor(wv0, 2); wv0 += __shfl_xor(wv0, 4);
    wv1 += __shfl_xor(wv1, 1); wv1 += __shfl_xor(wv1, 2); wv1 += __shfl_xor(wv1, 4);
    if (p == 0) { wv[kSa] = wv0; wv[kSa + 32] = wv1; }
  }
  __syncthreads();

  // ---- P3b: E = HS .* (A Gm^T) -> bf16 hi swz ; z1 partials ----
  {
    unsigned short* sEbf = (unsigned short*)sT1E;
    const f32x4 gr0 = *(const f32x4*)&sGm[l][0];
    const f32x4 gr1 = *(const f32x4*)&sGm[l][4];
    #pragma unroll 4
    for (int j = 0; j < 16; ++j) {
      const int kS = 4 * j + w;                       // wave-uniform
      const f32x4 a0v = *(const f32x4*)&sA[kS][0];
      const f32x4 a1v = *(const f32x4*)&sA[kS][4];
      const float e = (dot4(a0v, gr0) + dot4(a1v, gr1)) * HS[kS * 64 + l];
      sEbf[kS * 64 + (l ^ ((kS & 7) << 3))] = f2bf(e);
    }
    const float wvl = wv[l];
    float part = 0.f;
    #pragma unroll
    for (int j = 0; j < 16; ++j) {
      const int kk = 16 * w + j;
      part += __shfl(wvl, kk) * UG[kk * 64 + l];      // global, coalesced, L2
    }
    zp1[w][l] = part;
  }
  __syncthreads();

  // ---- P4: F = E UG^T via MFMA (hi-only); fuse z2 ----
  {
    const unsigned short* sEbf = (const unsigned short*)sT1E;
    f32x4 acc[4];
    #pragma unroll
    for (int nt = 0; nt < 4; ++nt) acc[nt] = (f32x4){0.f, 0.f, 0.f, 0.f};
    #pragma unroll
    for (int ks = 0; ks < 2; ++ks) {
      const int kcol = g * 8 + ks * 32;
      const int rowA = 16 * w + r;
      const bf16x8 ah = *(const bf16x8*)&sEbf[rowA * 64 + (kcol ^ ((rowA & 7) << 3))];
      #pragma unroll
      for (int nt = 0; nt < 4; ++nt) {
        const int rowB = 16 * nt + r;
        const bf16x8 bh = *(const bf16x8*)&sUGh[rowB * 64 + (kcol ^ ((rowB & 7) << 3))];
        acc[nt] = __builtin_amdgcn_mfma_f32_16x16x32_bf16(ah, bh, acc[nt], 0, 0, 0);
      }
    }
    #pragma unroll
    for (int nt = 0; nt < 4; ++nt) {
      float zp = 0.f;
      #pragma unroll
      for (int reg = 0; reg < 4; ++reg) {
        const int kS = 16 * w + 4 * g + reg;
        const int iS = 16 * nt + r;
        zp += bf2f(sUGh[iS * 64 + (kS ^ ((iS & 7) << 3))]) * acc[nt][reg];
      }
      zp += __shfl_xor(zp, 16);
      zp += __shfl_xor(zp, 32);
      if (g == 0) zpart[w][16 * nt + r] = zp;
    }
  }
  __syncthreads();

  // ---- P5: combine + write ----
  if (t < 64) {
    const float z2 = zpart[0][t] + zpart[1][t] + zpart[2][t] + zpart[3][t];
    const float z1 = zp1[0][t] + zp1[1][t] + zp1[2][t] + zp1[3][t];
    const int col = t * 32 + iT;
    out[b * 2048 + col] = h0[col] + z1 + z2;
  }
}

extern "C" void kernel_launch(void* const* d_in, const int* in_sizes, int n_in,
                              void* d_out, int out_size, void* d_ws, size_t ws_size,
                              hipStream_t stream) {
  const float* s   = (const float*)d_in[0];  // (16,2048)
  const float* UG  = (const float*)d_in[1];  // (64,64)
  const float* UPT = (const float*)d_in[2];  // (32,32)
  const float* h0  = (const float*)d_in[3];  // (2048,)
  const float* h1c = (const float*)d_in[4];  // (64,8)
  const float* HS  = (const float*)d_in[5];  // (64,64)
  const float* Hc  = (const float*)d_in[6];  // (8,8)
  float* out = (float*)d_out;

  volterra_one<<<512, 256, 0, stream>>>(s, UG, UPT, h0, h1c, HS, Hc, out);
}